// Round 3
// baseline (363.218 us; speedup 1.0000x reference)
//
#include <hip/hip_runtime.h>
#include <cmath>

namespace {

constexpr int N = 32, T = 1024, C = 512, K = 64;
constexpr float EPS = 1e-12f;
constexpr unsigned int MAGIC = 0x1F2E3D4Cu;  // non-repeated-byte: poison-safe

typedef short s8v __attribute__((ext_vector_type(8)));   // 8 x bf16 bits
typedef short s4v __attribute__((ext_vector_type(4)));   // 4 x bf16 bits
typedef short s2v __attribute__((ext_vector_type(2)));   // 2 x bf16 bits
typedef float f4v __attribute__((ext_vector_type(4)));   // MFMA accumulator

__device__ inline unsigned short f2bh(float f) {
  __bf16 h = (__bf16)f;
  return __builtin_bit_cast(unsigned short, h);
}
__device__ inline float bh2f(unsigned short u) {
  __bf16 h = __builtin_bit_cast(__bf16, u);
  return (float)h;
}

#define MFMA16(A, B, Cc) __builtin_amdgcn_mfma_f32_16x16x32_bf16((A), (B), (Cc), 0, 0, 0)

// Bounded acquire-spin on a device-scope flag. Budget ~0.2s worst case so a
// logic error fails with a numeric diff instead of hanging the container.
__device__ inline void wait_flag(const unsigned int* f) {
  int budget = 1 << 20;
  while (__hip_atomic_load(f, __ATOMIC_ACQUIRE, __HIP_MEMORY_SCOPE_AGENT) !=
             MAGIC &&
         --budget)
    __builtin_amdgcn_s_sleep(8);
}

// ---------------------------------------------------------------------------
// Fused persistent kernel: 512 blocks x 256 threads, all co-resident
// (LDS 37.9KB -> 4 blocks/CU; launch_bounds(256,4) -> <=128 VGPR).
// Phase 1 (gemm1): block (n, tl) computes logits/softmax for 64 t-rows,
//   writes aT + asum_part, release flags1[bid].
// Phase 2 (gemm2): block remaps (XCD-grouped) to (n2, cq2); acquire-waits
//   16 producer flags of n2, computes vlad 64k x 32c over full T, writes
//   vlad + ssq_part, release flags2[n2*16+cq2].
// Phase 3 (norm): block remaps to (n3, chunk); acquire-waits 16 ssq flags
//   of n3, normalizes and writes out.
// All phase bodies verbatim from the 3-kernel version (identical numerics).
// ---------------------------------------------------------------------------
__global__ __launch_bounds__(256, 4) void k_fused(
    const float* __restrict__ x, const float* __restrict__ W,
    const float* __restrict__ b, const float* __restrict__ cent,
    float* __restrict__ out, float* __restrict__ aT, float* __restrict__ vlad,
    float* __restrict__ asum_part, float* __restrict__ ssq_part,
    unsigned int* __restrict__ flags1, unsigned int* __restrict__ flags2) {
  __shared__ __align__(16) unsigned char smraw[36864 + 1024];

  const int tid = threadIdx.x;
  const int bid = blockIdx.x;
  const int w = tid >> 6, lane = tid & 63, lm = lane & 15, lq = lane >> 4;

  // ======================= phase 1: logits + softmax =======================
  {
    unsigned short* sm = (unsigned short*)smraw;
    float* asum_l = (float*)(smraw + 36864);  // 256 floats
    unsigned short* xh_s = sm;                // [64 t][72] bf16
    unsigned short* xl_s = sm + 64 * 72;
    unsigned short* wh_s = sm + 2 * 64 * 72;  // [64 k][72]
    unsigned short* wl_s = sm + 3 * 64 * 72;

    const int th = w >> 1;  // t-half (32 rows)
    const int kh = w & 1;   // k-half (32 cols)
    const long r0 = (long)bid * 64;
    const int n = bid >> 4, tl = bid & 15;

    f4v acc[2][2] = {};
    float4 px[4], pw[4];
#pragma unroll
    for (int r = 0; r < 4; ++r) {
      const int f = tid + r * 256, t = f >> 4, cg = f & 15;
      px[r] = *(const float4*)&x[(r0 + t) * C + cg * 4];
      pw[r] = *(const float4*)&W[(long)t * C + cg * 4];
    }

    for (int c0 = 0; c0 < C; c0 += 64) {
      __syncthreads();
#pragma unroll
      for (int r = 0; r < 4; ++r) {
        const int f = tid + r * 256, t = f >> 4, cg = f & 15;
        const float ex[4] = {px[r].x, px[r].y, px[r].z, px[r].w};
        const float ew[4] = {pw[r].x, pw[r].y, pw[r].z, pw[r].w};
        s4v xh, xl, wh, wl;
#pragma unroll
        for (int i = 0; i < 4; ++i) {
          unsigned short hb = f2bh(ex[i]);
          xh[i] = (short)hb; xl[i] = (short)f2bh(ex[i] - bh2f(hb));
          hb = f2bh(ew[i]);
          wh[i] = (short)hb; wl[i] = (short)f2bh(ew[i] - bh2f(hb));
        }
        *(s4v*)&xh_s[t * 72 + cg * 4] = xh;
        *(s4v*)&xl_s[t * 72 + cg * 4] = xl;
        *(s4v*)&wh_s[t * 72 + cg * 4] = wh;
        *(s4v*)&wl_s[t * 72 + cg * 4] = wl;
      }
      __syncthreads();
      if (c0 + 64 < C) {  // prefetch next chunk (in flight across MFMA)
#pragma unroll
        for (int r = 0; r < 4; ++r) {
          const int f = tid + r * 256, t = f >> 4, cg = f & 15;
          px[r] = *(const float4*)&x[(r0 + t) * C + c0 + 64 + cg * 4];
          pw[r] = *(const float4*)&W[(long)t * C + c0 + 64 + cg * 4];
        }
      }

#pragma unroll
      for (int ks = 0; ks < 2; ++ks) {
        const int col = ks * 32 + lq * 8;
        s8v ah[2], al[2], bh[2], bl[2];
#pragma unroll
        for (int i = 0; i < 2; ++i) {
          ah[i] = *(const s8v*)&xh_s[(th * 32 + i * 16 + lm) * 72 + col];
          al[i] = *(const s8v*)&xl_s[(th * 32 + i * 16 + lm) * 72 + col];
          bh[i] = *(const s8v*)&wh_s[(kh * 32 + i * 16 + lm) * 72 + col];
          bl[i] = *(const s8v*)&wl_s[(kh * 32 + i * 16 + lm) * 72 + col];
        }
#pragma unroll
        for (int i = 0; i < 2; ++i)
#pragma unroll
          for (int j = 0; j < 2; ++j) {
            acc[i][j] = MFMA16(ah[i], bh[j], acc[i][j]);
            acc[i][j] = MFMA16(ah[i], bl[j], acc[i][j]);
            acc[i][j] = MFMA16(al[i], bh[j], acc[i][j]);
          }
      }
    }
    __syncthreads();

    // logits + bias -> LDS Ls[64 t][68] fp32 ; Ls2 = a^T staging [64 k][68]
    float* Ls = (float*)sm;            // 17408 B
    float* Ls2 = (float*)((unsigned char*)sm + 8704);  // 17408 B
    const float bias[2] = {b[kh * 32 + lm], b[kh * 32 + 16 + lm]};
#pragma unroll
    for (int i = 0; i < 2; ++i)
#pragma unroll
      for (int j = 0; j < 2; ++j)
#pragma unroll
        for (int r = 0; r < 4; ++r)
          Ls[(th * 32 + i * 16 + lq * 4 + r) * 68 + kh * 32 + j * 16 + lm] =
              acc[i][j][r] + bias[j];
    __syncthreads();

    // softmax: 4 threads per t-row, 16 k each, register + shfl
    {
      const int row = tid >> 2, q = tid & 3;
      float av[16];
#pragma unroll
      for (int u = 0; u < 4; ++u)
        *(float4*)&av[u * 4] = *(const float4*)&Ls[row * 68 + q * 16 + u * 4];
      float m = av[0];
#pragma unroll
      for (int i = 1; i < 16; ++i) m = fmaxf(m, av[i]);
      m = fmaxf(m, __shfl_xor(m, 1, 64));
      m = fmaxf(m, __shfl_xor(m, 2, 64));
      float sum = 0.f;
#pragma unroll
      for (int i = 0; i < 16; ++i) {
        av[i] = __expf(av[i] - m);
        sum += av[i];
      }
      sum += __shfl_xor(sum, 1, 64);
      sum += __shfl_xor(sum, 2, 64);
      const float inv = 1.f / sum;
      float ps[16];
#pragma unroll
      for (int i = 0; i < 16; ++i) {
        av[i] *= inv;
        ps[i] = av[i];
        Ls2[(q * 16 + i) * 68 + row] = av[i];  // transposed a^T [k][t]
      }
#pragma unroll
      for (int s = 4; s < 64; s <<= 1)
#pragma unroll
        for (int i = 0; i < 16; ++i) ps[i] += __shfl_xor(ps[i], s, 64);
      if (lane < 4) {
#pragma unroll
        for (int i = 0; i < 16; ++i) asum_l[w * 64 + q * 16 + i] = ps[i];
      }
    }
    __syncthreads();

    if (tid < 64) {
      asum_part[(n * 16 + tl) * 64 + tid] = asum_l[tid] + asum_l[64 + tid] +
                                            asum_l[128 + tid] +
                                            asum_l[192 + tid];
    }
#pragma unroll
    for (int r = 0; r < 4; ++r) {
      const int u = tid + r * 256, k = u >> 4, tg = u & 15;
      *(float4*)&aT[((long)n * K + k) * T + tl * 64 + tg * 4] =
          *(const float4*)&Ls2[k * 68 + tg * 4];
    }
  }

  // release: aT + asum_part of this block are globally visible
  __threadfence();
  __syncthreads();
  if (tid == 0)
    __hip_atomic_store(&flags1[bid], MAGIC, __ATOMIC_RELEASE,
                       __HIP_MEMORY_SCOPE_AGENT);

  // ======================= phase 2: vlad GEMM ==============================
  int n2, cq2;
  {
    const int g = bid >> 3;
    n2 = ((g & 3) << 3) | (bid & 7);  // XCD-grouping bijection
    cq2 = g >> 2;
  }
  if (tid < 16) wait_flag(&flags1[n2 * 16 + tid]);
  __syncthreads();
  __threadfence();

  {
    unsigned short* sm = (unsigned short*)smraw;  // 27648 B used
    float* asum_l = (float*)(smraw + 28672);      // 64 floats
    float* ssq_l = (float*)(smraw + 28928);       // 128 floats
    unsigned short* ah_s = sm;                // a^T hi [64 k][72]
    unsigned short* al_s = sm + 64 * 72;
    unsigned short* xh_s = sm + 2 * 64 * 72;  // x^T hi [32 c][72]
    unsigned short* xl_s = sm + 2 * 64 * 72 + 32 * 72;

    const int kh = w >> 1;  // 32k half
    const int ch = w & 1;   // 16c half
    const int n = n2, cq = cq2;
    const int c0 = cq * 32;

    if (tid < 64) {
      float s = 0.f;
#pragma unroll
      for (int tl = 0; tl < 16; ++tl) s += asum_part[(n * 16 + tl) * 64 + tid];
      asum_l[tid] = s;
    }

    f4v acc[2] = {};
    float4 pa[4], px[2];
#pragma unroll
    for (int r = 0; r < 4; ++r) {
      const int u = tid + r * 256, k = u >> 4, tg = u & 15;
      pa[r] = *(const float4*)&aT[((long)n * K + k) * T + tg * 4];
    }
    {
      const int cg = tid & 7, tq = tid >> 3;
#pragma unroll
      for (int i = 0; i < 2; ++i)
        px[i] = *(const float4*)&x[((long)n * T + tq * 2 + i) * C + c0 + cg * 4];
    }

    for (int t0 = 0; t0 < T; t0 += 64) {
      __syncthreads();
#pragma unroll
      for (int r = 0; r < 4; ++r) {
        const int u = tid + r * 256, k = u >> 4, tg = u & 15;
        const float e[4] = {pa[r].x, pa[r].y, pa[r].z, pa[r].w};
        s4v h, l;
#pragma unroll
        for (int i = 0; i < 4; ++i) {
          unsigned short hb = f2bh(e[i]);
          h[i] = (short)hb;
          l[i] = (short)f2bh(e[i] - bh2f(hb));
        }
        *(s4v*)&ah_s[k * 72 + tg * 4] = h;
        *(s4v*)&al_s[k * 72 + tg * 4] = l;
      }
      {
        const int cg = tid & 7, tq = tid >> 3;
#pragma unroll
        for (int cc = 0; cc < 4; ++cc) {
          s2v h, l;
#pragma unroll
          for (int i = 0; i < 2; ++i) {
            const float e = ((const float*)&px[i])[cc];
            unsigned short hb = f2bh(e);
            h[i] = (short)hb;
            l[i] = (short)f2bh(e - bh2f(hb));
          }
          *(s2v*)&xh_s[(cg * 4 + cc) * 72 + tq * 2] = h;
          *(s2v*)&xl_s[(cg * 4 + cc) * 72 + tq * 2] = l;
        }
      }
      __syncthreads();
      if (t0 + 64 < T) {  // prefetch next t-tile (in flight across MFMA)
#pragma unroll
        for (int r = 0; r < 4; ++r) {
          const int u = tid + r * 256, k = u >> 4, tg = u & 15;
          pa[r] = *(const float4*)&aT[((long)n * K + k) * T + t0 + 64 + tg * 4];
        }
        const int cg = tid & 7, tq = tid >> 3;
#pragma unroll
        for (int i = 0; i < 2; ++i)
          px[i] = *(const float4*)&x[((long)n * T + t0 + 64 + tq * 2 + i) * C +
                                     c0 + cg * 4];
      }

#pragma unroll
      for (int ks = 0; ks < 2; ++ks) {
        const int col = ks * 32 + lq * 8;
        s8v ah[2], al[2];
#pragma unroll
        for (int i = 0; i < 2; ++i) {
          ah[i] = *(const s8v*)&ah_s[(kh * 32 + i * 16 + lm) * 72 + col];
          al[i] = *(const s8v*)&al_s[(kh * 32 + i * 16 + lm) * 72 + col];
        }
        const s8v bh = *(const s8v*)&xh_s[(ch * 16 + lm) * 72 + col];
        const s8v bl = *(const s8v*)&xl_s[(ch * 16 + lm) * 72 + col];
#pragma unroll
        for (int i = 0; i < 2; ++i) {
          acc[i] = MFMA16(ah[i], bh, acc[i]);
          acc[i] = MFMA16(ah[i], bl, acc[i]);
          acc[i] = MFMA16(al[i], bh, acc[i]);
        }
      }
    }

    // fused epilogue: subtract asum*cent, write vlad, ssq partials
    float ssqp[2][4];
#pragma unroll
    for (int i = 0; i < 2; ++i) {
#pragma unroll
      for (int r = 0; r < 4; ++r) {
        const int k = kh * 32 + i * 16 + lq * 4 + r;
        const float as = asum_l[k];
        const int c = c0 + ch * 16 + lm;
        const float v = acc[i][r] - as * cent[(long)k * C + c];
        vlad[((long)n * K + k) * C + c] = v;
        ssqp[i][r] = v * v;
      }
    }
#pragma unroll
    for (int i = 0; i < 2; ++i)
#pragma unroll
      for (int r = 0; r < 4; ++r) {
        float s = ssqp[i][r];
        s += __shfl_xor(s, 1, 64);
        s += __shfl_xor(s, 2, 64);
        s += __shfl_xor(s, 4, 64);
        s += __shfl_xor(s, 8, 64);
        ssqp[i][r] = s;
      }
    if (lm == 0) {
#pragma unroll
      for (int i = 0; i < 2; ++i)
#pragma unroll
        for (int r = 0; r < 4; ++r)
          ssq_l[(kh * 32 + i * 16 + lq * 4 + r) * 2 + ch] = ssqp[i][r];
    }
    __syncthreads();
    if (tid < 64)
      ssq_part[(n * 16 + cq) * 64 + tid] = ssq_l[tid * 2] + ssq_l[tid * 2 + 1];
  }

  // release: vlad + ssq_part of this (n2, cq2) are globally visible
  __threadfence();
  __syncthreads();
  if (tid == 0)
    __hip_atomic_store(&flags2[n2 * 16 + cq2], MAGIC, __ATOMIC_RELEASE,
                       __HIP_MEMORY_SCOPE_AGENT);

  // ======================= phase 3: normalize ==============================
  const int n3 = bid >> 4, chunk = bid & 15;
  if (tid < 16) wait_flag(&flags2[n3 * 16 + tid]);
  __syncthreads();
  __threadfence();

  {
    float* denom = (float*)smraw;
    float* contrib = denom + 64;
    float* ginvp = contrib + 64;

    if (tid < 64) {
      float ss = 0.f;
#pragma unroll
      for (int q = 0; q < 16; ++q) ss += ssq_part[(n3 * 16 + q) * 64 + tid];
      const float d = fmaxf(sqrtf(ss), EPS);
      denom[tid] = d;
      contrib[tid] = ss / (d * d);
    }
    __syncthreads();
    if (tid == 0) {
      float s = 0.f;
#pragma unroll
      for (int k = 0; k < K; ++k) s += contrib[k];
      *ginvp = 1.0f / fmaxf(sqrtf(s), EPS);
    }
    __syncthreads();
    const float ginv = *ginvp;

#pragma unroll
    for (int q = 0; q < 2; ++q) {
      const int f4 = tid + q * 256;
      const long off = chunk * 2048 + (long)f4 * 4;
      const int k = (int)(off >> 9);
      float4 v = *(const float4*)&vlad[(long)n3 * K * C + off];
      const float sc = ginv / denom[k];
      v.x *= sc; v.y *= sc; v.z *= sc; v.w *= sc;
      *(float4*)&out[(long)n3 * K * C + off] = v;
    }
  }
}

}  // namespace

extern "C" void kernel_launch(void* const* d_in, const int* in_sizes, int n_in,
                              void* d_out, int out_size, void* d_ws,
                              size_t ws_size, hipStream_t stream) {
  const float* x = reinterpret_cast<const float*>(d_in[0]);     // [N,T,C]
  const float* W = reinterpret_cast<const float*>(d_in[1]);     // [K,C]
  const float* b = reinterpret_cast<const float*>(d_in[2]);     // [K]
  const float* cent = reinterpret_cast<const float*>(d_in[3]);  // [K,C]
  float* out = reinterpret_cast<float*>(d_out);                 // [N, K*C]

  float* p = reinterpret_cast<float*>(d_ws);
  float* aTg = p;                 p += (size_t)N * K * T;   // 8 MiB
  float* vlad = p;                p += (size_t)N * K * C;   // 4 MiB
  float* asum_part = p;           p += (size_t)512 * 64;    // 128 KiB
  float* ssq_part = p;            p += (size_t)512 * 64;    // 128 KiB
  unsigned int* flags1 = reinterpret_cast<unsigned int*>(p);
  unsigned int* flags2 = flags1 + 512;

  k_fused<<<512, 256, 0, stream>>>(x, W, b, cent, out, aTg, vlad, asum_part,
                                   ssq_part, flags1, flags2);
}

// Round 4
// 130.946 us; speedup vs baseline: 2.7738x; 2.7738x over previous
//
#include <hip/hip_runtime.h>
#include <cmath>

namespace {

constexpr int N = 32, T = 1024, C = 512, K = 64;
constexpr float EPS = 1e-12f;

typedef short s8v __attribute__((ext_vector_type(8)));   // 8 x bf16 bits
typedef short s4v __attribute__((ext_vector_type(4)));   // 4 x bf16 bits
typedef float f4v __attribute__((ext_vector_type(4)));   // MFMA accumulator

__device__ inline unsigned short f2bh(float f) {
  __bf16 h = (__bf16)f;
  return __builtin_bit_cast(unsigned short, h);
}
__device__ inline float bh2f(unsigned short u) {
  __bf16 h = __builtin_bit_cast(__bf16, u);
  return (float)h;
}

#define MFMA16(A, B, Cc) __builtin_amdgcn_mfma_f32_16x16x32_bf16((A), (B), (Cc), 0, 0, 0)

// ---------------------------------------------------------------------------
// k_gemm1: logits = x @ W^T + b (split-bf16 3-pass MFMA), softmax over K,
// writes a^T [n][k][t] fp32 + asum_part[block][64].
// R4: 512 threads (8 waves) per block, same 64t x 64k tile -> 16 waves/CU
// (2 blocks/CU) instead of 8. Grid NT/64 = 512. Wave = 32t x 16k, acc[2].
// Latency-bound per R3 counters (all pipes <5% busy, occupancy grid-capped).
// ---------------------------------------------------------------------------
__global__ __launch_bounds__(512, 4) void k_gemm1(
    const float* __restrict__ x, const float* __restrict__ W,
    const float* __restrict__ b, float* __restrict__ aT,
    float* __restrict__ asum_part) {
  __shared__ __align__(16) unsigned short sm[4 * 64 * 72];  // 36864 B
  __shared__ float asum_l[512];
  unsigned short* xh_s = sm;                // [64 t][72] bf16
  unsigned short* xl_s = sm + 64 * 72;
  unsigned short* wh_s = sm + 2 * 64 * 72;  // [64 k][72]
  unsigned short* wl_s = sm + 3 * 64 * 72;

  const int tid = threadIdx.x;
  const int w = tid >> 6, lane = tid & 63, lm = lane & 15, lq = lane >> 4;
  const int th = w >> 2;  // t-half (32 rows)
  const int kq = w & 3;   // k-quarter (16 cols)
  const long r0 = (long)blockIdx.x * 64;
  const int n = blockIdx.x >> 4, tl = blockIdx.x & 15;

  f4v acc[2] = {};
  float4 px[2], pw[2];
#pragma unroll
  for (int r = 0; r < 2; ++r) {
    const int f = tid + r * 512, t = f >> 4, cg = f & 15;
    px[r] = *(const float4*)&x[(r0 + t) * C + cg * 4];
    pw[r] = *(const float4*)&W[(long)t * C + cg * 4];
  }

  for (int c0 = 0; c0 < C; c0 += 64) {
    __syncthreads();
#pragma unroll
    for (int r = 0; r < 2; ++r) {
      const int f = tid + r * 512, t = f >> 4, cg = f & 15;
      const float ex[4] = {px[r].x, px[r].y, px[r].z, px[r].w};
      const float ew[4] = {pw[r].x, pw[r].y, pw[r].z, pw[r].w};
      s4v xh, xl, wh, wl;
#pragma unroll
      for (int i = 0; i < 4; ++i) {
        unsigned short hb = f2bh(ex[i]);
        xh[i] = (short)hb; xl[i] = (short)f2bh(ex[i] - bh2f(hb));
        hb = f2bh(ew[i]);
        wh[i] = (short)hb; wl[i] = (short)f2bh(ew[i] - bh2f(hb));
      }
      *(s4v*)&xh_s[t * 72 + cg * 4] = xh;
      *(s4v*)&xl_s[t * 72 + cg * 4] = xl;
      *(s4v*)&wh_s[t * 72 + cg * 4] = wh;
      *(s4v*)&wl_s[t * 72 + cg * 4] = wl;
    }
    __syncthreads();
    if (c0 + 64 < C) {  // prefetch next chunk (in flight across MFMA phase)
#pragma unroll
      for (int r = 0; r < 2; ++r) {
        const int f = tid + r * 512, t = f >> 4, cg = f & 15;
        px[r] = *(const float4*)&x[(r0 + t) * C + c0 + 64 + cg * 4];
        pw[r] = *(const float4*)&W[(long)t * C + c0 + 64 + cg * 4];
      }
    }

#pragma unroll
    for (int ks = 0; ks < 2; ++ks) {
      const int col = ks * 32 + lq * 8;
      s8v ah[2], al[2];
#pragma unroll
      for (int i = 0; i < 2; ++i) {
        ah[i] = *(const s8v*)&xh_s[(th * 32 + i * 16 + lm) * 72 + col];
        al[i] = *(const s8v*)&xl_s[(th * 32 + i * 16 + lm) * 72 + col];
      }
      const s8v bh = *(const s8v*)&wh_s[(kq * 16 + lm) * 72 + col];
      const s8v bl = *(const s8v*)&wl_s[(kq * 16 + lm) * 72 + col];
#pragma unroll
      for (int i = 0; i < 2; ++i) {
        acc[i] = MFMA16(ah[i], bh, acc[i]);
        acc[i] = MFMA16(ah[i], bl, acc[i]);
        acc[i] = MFMA16(al[i], bh, acc[i]);
      }
    }
  }
  __syncthreads();

  // logits + bias -> LDS Ls[64 t][68] fp32 ; Ls2 = a^T staging [64 k][68]
  float* Ls = (float*)sm;            // 17408 B
  float* Ls2 = (float*)((unsigned char*)sm + 17408);  // 17408 B
  const float bias = b[kq * 16 + lm];
#pragma unroll
  for (int i = 0; i < 2; ++i)
#pragma unroll
    for (int r = 0; r < 4; ++r)
      Ls[(th * 32 + i * 16 + lq * 4 + r) * 68 + kq * 16 + lm] =
          acc[i][r] + bias;
  __syncthreads();

  // softmax: 8 threads per t-row, 8 k each, register + shfl
  {
    const int row = tid >> 3, q = tid & 7;
    float av[8];
#pragma unroll
    for (int u = 0; u < 2; ++u)
      *(float4*)&av[u * 4] = *(const float4*)&Ls[row * 68 + q * 8 + u * 4];
    float m = av[0];
#pragma unroll
    for (int i = 1; i < 8; ++i) m = fmaxf(m, av[i]);
    m = fmaxf(m, __shfl_xor(m, 1, 64));
    m = fmaxf(m, __shfl_xor(m, 2, 64));
    m = fmaxf(m, __shfl_xor(m, 4, 64));
    float sum = 0.f;
#pragma unroll
    for (int i = 0; i < 8; ++i) {
      av[i] = __expf(av[i] - m);
      sum += av[i];
    }
    sum += __shfl_xor(sum, 1, 64);
    sum += __shfl_xor(sum, 2, 64);
    sum += __shfl_xor(sum, 4, 64);
    const float inv = 1.f / sum;
    float ps[8];
#pragma unroll
    for (int i = 0; i < 8; ++i) {
      av[i] *= inv;
      ps[i] = av[i];
      Ls2[(q * 8 + i) * 68 + row] = av[i];  // transposed a^T [k][t]
    }
#pragma unroll
    for (int s = 8; s < 64; s <<= 1)
#pragma unroll
      for (int i = 0; i < 8; ++i) ps[i] += __shfl_xor(ps[i], s, 64);
    if (lane < 8) {
#pragma unroll
      for (int i = 0; i < 8; ++i) asum_l[w * 64 + q * 8 + i] = ps[i];
    }
  }
  __syncthreads();

  if (tid < 64) {
    float s = 0.f;
#pragma unroll
    for (int j = 0; j < 8; ++j) s += asum_l[j * 64 + tid];
    asum_part[(n * 16 + tl) * 64 + tid] = s;
  }
#pragma unroll
  for (int r = 0; r < 2; ++r) {
    const int u = tid + r * 512, k = u >> 4, tg = u & 15;
    *(float4*)&aT[((long)n * K + k) * T + tl * 64 + tg * 4] =
        *(const float4*)&Ls2[k * 68 + tg * 4];
  }
}

// ---------------------------------------------------------------------------
// k_gemm2: vlad[n,k,c] = sum_t a[t,k]*x[t,c] - asum*cent, full T per block.
// R4: 512 threads (8 waves), same 64k x 32c tile -> 16 waves/CU. Grid N*16
// with XCD-grouping swizzle. Wave = 16k x 16c, acc[1]. Fused epilogue.
// ---------------------------------------------------------------------------
__global__ __launch_bounds__(512, 4) void k_gemm2(
    const float* __restrict__ x, const float* __restrict__ aT,
    const float* __restrict__ asum_part, const float* __restrict__ cent,
    float* __restrict__ vlad, float* __restrict__ ssq_part) {
  __shared__ __align__(16) unsigned short sm[(2 * 64 + 2 * 32) * 72];  // 27648 B
  __shared__ float asum_l[64];
  __shared__ float ssq_l[128];
  unsigned short* ah_s = sm;                // a^T hi [64 k][72]
  unsigned short* al_s = sm + 64 * 72;
  unsigned short* xh_s = sm + 2 * 64 * 72;  // x^T hi [32 c][72]
  unsigned short* xl_s = sm + 2 * 64 * 72 + 32 * 72;

  const int tid = threadIdx.x;
  const int w = tid >> 6, lane = tid & 63, lm = lane & 15, lq = lane >> 4;
  const int kh = w >> 1;  // 16k quarter
  const int ch = w & 1;   // 16c half
  // XCD-grouping bijection: all 16 c-chunk blocks of an n on one XCD
  const int p = blockIdx.x;
  const int g = p >> 3;
  const int n = ((g & 3) << 3) | (p & 7);
  const int cq = g >> 2;
  const int c0 = cq * 32;

  if (tid < 64) {
    float s = 0.f;
#pragma unroll
    for (int tl = 0; tl < 16; ++tl) s += asum_part[(n * 16 + tl) * 64 + tid];
    asum_l[tid] = s;
  }

  f4v acc = {};
  float4 pa[2], px;
  // preload tile 0
#pragma unroll
  for (int r = 0; r < 2; ++r) {
    const int u = tid + r * 512, k = u >> 4, tg = u & 15;
    pa[r] = *(const float4*)&aT[((long)n * K + k) * T + tg * 4];
  }
  {
    const int cg = tid & 7, tq = tid >> 3;  // tq in [0,64), 1 t each
    px = *(const float4*)&x[((long)n * T + tq) * C + c0 + cg * 4];
  }

  for (int t0 = 0; t0 < T; t0 += 64) {
    __syncthreads();
    // a^T: fp32 -> hi/lo
#pragma unroll
    for (int r = 0; r < 2; ++r) {
      const int u = tid + r * 512, k = u >> 4, tg = u & 15;
      const float e[4] = {pa[r].x, pa[r].y, pa[r].z, pa[r].w};
      s4v h, l;
#pragma unroll
      for (int i = 0; i < 4; ++i) {
        unsigned short hb = f2bh(e[i]);
        h[i] = (short)hb;
        l[i] = (short)f2bh(e[i] - bh2f(hb));
      }
      *(s4v*)&ah_s[k * 72 + tg * 4] = h;
      *(s4v*)&al_s[k * 72 + tg * 4] = l;
    }
    // x^T: fp32 -> hi/lo, transposed scalar writes (32 c rows x 64 t)
    {
      const int cg = tid & 7, tq = tid >> 3;
      const float e4[4] = {px.x, px.y, px.z, px.w};
#pragma unroll
      for (int cc = 0; cc < 4; ++cc) {
        const float e = e4[cc];
        const unsigned short hb = f2bh(e);
        xh_s[(cg * 4 + cc) * 72 + tq] = hb;
        xl_s[(cg * 4 + cc) * 72 + tq] = f2bh(e - bh2f(hb));
      }
    }
    __syncthreads();
    if (t0 + 64 < T) {  // prefetch next t-tile (in flight across MFMA phase)
#pragma unroll
      for (int r = 0; r < 2; ++r) {
        const int u = tid + r * 512, k = u >> 4, tg = u & 15;
        pa[r] = *(const float4*)&aT[((long)n * K + k) * T + t0 + 64 + tg * 4];
      }
      const int cg = tid & 7, tq = tid >> 3;
      px = *(const float4*)&x[((long)n * T + t0 + 64 + tq) * C + c0 + cg * 4];
    }

#pragma unroll
    for (int ks = 0; ks < 2; ++ks) {
      const int col = ks * 32 + lq * 8;
      const s8v ah = *(const s8v*)&ah_s[(kh * 16 + lm) * 72 + col];
      const s8v al = *(const s8v*)&al_s[(kh * 16 + lm) * 72 + col];
      const s8v bh = *(const s8v*)&xh_s[(ch * 16 + lm) * 72 + col];
      const s8v bl = *(const s8v*)&xl_s[(ch * 16 + lm) * 72 + col];
      acc = MFMA16(ah, bh, acc);
      acc = MFMA16(ah, bl, acc);
      acc = MFMA16(al, bh, acc);
    }
  }

  // fused epilogue: subtract asum*cent, write vlad, ssq partials
  float ssqp[4];
#pragma unroll
  for (int r = 0; r < 4; ++r) {
    const int k = kh * 16 + lq * 4 + r;
    const float as = asum_l[k];
    const int c = c0 + ch * 16 + lm;
    const float v = acc[r] - as * cent[(long)k * C + c];
    vlad[((long)n * K + k) * C + c] = v;
    ssqp[r] = v * v;
  }
#pragma unroll
  for (int r = 0; r < 4; ++r) {
    float s = ssqp[r];
    s += __shfl_xor(s, 1, 64);
    s += __shfl_xor(s, 2, 64);
    s += __shfl_xor(s, 4, 64);
    s += __shfl_xor(s, 8, 64);
    ssqp[r] = s;
  }
  if (lm == 0) {
#pragma unroll
    for (int r = 0; r < 4; ++r)
      ssq_l[(kh * 16 + lq * 4 + r) * 2 + ch] = ssqp[r];
  }
  __syncthreads();
  if (tid < 64)
    ssq_part[(n * 16 + cq) * 64 + tid] = ssq_l[tid * 2] + ssq_l[tid * 2 + 1];
}

// ---------------------------------------------------------------------------
// k_norm: out = vlad / (||vlad_k|| * ||intra-normed||). Grid N*16 x 256.
// ---------------------------------------------------------------------------
__global__ __launch_bounds__(256) void k_norm(
    const float* __restrict__ vlad, const float* __restrict__ ssq_part,
    float* __restrict__ out) {
  __shared__ float denom[64];
  __shared__ float contrib[64];
  __shared__ float ginv;

  const int tid = threadIdx.x;
  const int n = blockIdx.x >> 4;
  const int chunk = blockIdx.x & 15;

  if (tid < 64) {
    float ss = 0.f;
#pragma unroll
    for (int q = 0; q < 16; ++q) ss += ssq_part[(n * 16 + q) * 64 + tid];
    const float d = fmaxf(sqrtf(ss), EPS);
    denom[tid] = d;
    contrib[tid] = ss / (d * d);
  }
  __syncthreads();
  if (tid == 0) {
    float s = 0.f;
#pragma unroll
    for (int k = 0; k < K; ++k) s += contrib[k];
    ginv = 1.0f / fmaxf(sqrtf(s), EPS);
  }
  __syncthreads();

#pragma unroll
  for (int q = 0; q < 2; ++q) {
    const int f4 = tid + q * 256;
    const long off = chunk * 2048 + (long)f4 * 4;
    const int k = (int)(off >> 9);
    float4 v = *(const float4*)&vlad[(long)n * K * C + off];
    const float sc = ginv / denom[k];
    v.x *= sc; v.y *= sc; v.z *= sc; v.w *= sc;
    *(float4*)&out[(long)n * K * C + off] = v;
  }
}

}  // namespace

extern "C" void kernel_launch(void* const* d_in, const int* in_sizes, int n_in,
                              void* d_out, int out_size, void* d_ws,
                              size_t ws_size, hipStream_t stream) {
  const float* x = reinterpret_cast<const float*>(d_in[0]);     // [N,T,C]
  const float* W = reinterpret_cast<const float*>(d_in[1]);     // [K,C]
  const float* b = reinterpret_cast<const float*>(d_in[2]);     // [K]
  const float* cent = reinterpret_cast<const float*>(d_in[3]);  // [K,C]
  float* out = reinterpret_cast<float*>(d_out);                 // [N, K*C]

  float* p = reinterpret_cast<float*>(d_ws);
  float* aTg = p;                 p += (size_t)N * K * T;   // 8 MiB
  float* vlad = p;                p += (size_t)N * K * C;   // 4 MiB
  float* asum_part = p;           p += (size_t)512 * 64;    // 128 KiB
  float* ssq_part = p;            // 128 KiB

  k_gemm1<<<(N * T) / 64, 512, 0, stream>>>(x, W, b, aTg, asum_part);
  k_gemm2<<<N * 16, 512, 0, stream>>>(x, aTg, asum_part, cent, vlad, ssq_part);
  k_norm<<<N * 16, 256, 0, stream>>>(vlad, ssq_part, out);
}

// Round 5
// 127.283 us; speedup vs baseline: 2.8536x; 1.0288x over previous
//
#include <hip/hip_runtime.h>
#include <cmath>

namespace {

constexpr int N = 32, T = 1024, C = 512, K = 64;
constexpr float EPS = 1e-12f;

typedef short s8v __attribute__((ext_vector_type(8)));   // 8 x bf16 bits
typedef short s4v __attribute__((ext_vector_type(4)));   // 4 x bf16 bits
typedef short s2v __attribute__((ext_vector_type(2)));   // 2 x bf16 bits
typedef float f4v __attribute__((ext_vector_type(4)));   // MFMA accumulator

__device__ inline unsigned short f2bh(float f) {
  __bf16 h = (__bf16)f;
  return __builtin_bit_cast(unsigned short, h);
}
__device__ inline float bh2f(unsigned short u) {
  __bf16 h = __builtin_bit_cast(__bf16, u);
  return (float)h;
}

#define MFMA16(A, B, Cc) __builtin_amdgcn_mfma_f32_16x16x32_bf16((A), (B), (Cc), 0, 0, 0)

// ---------------------------------------------------------------------------
// k_gemm1: logits = x @ W^T + b (split-bf16 3-pass MFMA), softmax over K.
// R5: double-buffered LDS, ONE barrier per 64-c chunk (was 2); staging of
// chunk i+1 overlaps MFMA of chunk i. Writes a^T as bf16 HI/LO ushort arrays
// (gemm2 consumes directly -> no per-tile conversion there). 256 thr, grid 512.
// ---------------------------------------------------------------------------
__global__ __launch_bounds__(256, 4) void k_gemm1(
    const float* __restrict__ x, const float* __restrict__ W,
    const float* __restrict__ b, unsigned short* __restrict__ aTh,
    unsigned short* __restrict__ aTl, float* __restrict__ asum_part) {
  __shared__ __align__(16) unsigned short sm0[4 * 64 * 72];  // 36864 B
  __shared__ __align__(16) unsigned short sm1[4 * 64 * 72];  // 36864 B
  __shared__ float asum_l[256];

  const int tid = threadIdx.x;
  const int w = tid >> 6, lane = tid & 63, lm = lane & 15, lq = lane >> 4;
  const int th = w >> 1;  // t-half (32 rows)
  const int kh = w & 1;   // k-half (32 cols)
  const long r0 = (long)blockIdx.x * 64;
  const int n = blockIdx.x >> 4, tl = blockIdx.x & 15;

  f4v acc[2][2] = {};
  float4 px0[4], pw0[4], px1[4], pw1[4];

#define G1_LOAD(s, c0)                                                       \
  {                                                                          \
    _Pragma("unroll") for (int r = 0; r < 4; ++r) {                          \
      const int f = tid + r * 256, t = f >> 4, cg = f & 15;                  \
      px##s[r] = *(const float4*)&x[(r0 + t) * C + (c0) + cg * 4];           \
      pw##s[r] = *(const float4*)&W[(long)t * C + (c0) + cg * 4];            \
    }                                                                        \
  }

#define G1_STAGE(buf, s)                                                     \
  {                                                                          \
    unsigned short* xh_s = (buf);                                            \
    unsigned short* xl_s = (buf) + 64 * 72;                                  \
    unsigned short* wh_s = (buf) + 2 * 64 * 72;                              \
    unsigned short* wl_s = (buf) + 3 * 64 * 72;                              \
    _Pragma("unroll") for (int r = 0; r < 4; ++r) {                          \
      const int f = tid + r * 256, t = f >> 4, cg = f & 15;                  \
      const float ex[4] = {px##s[r].x, px##s[r].y, px##s[r].z, px##s[r].w};  \
      const float ew[4] = {pw##s[r].x, pw##s[r].y, pw##s[r].z, pw##s[r].w};  \
      s4v xh, xl, wh, wl;                                                    \
      _Pragma("unroll") for (int i = 0; i < 4; ++i) {                        \
        unsigned short hb = f2bh(ex[i]);                                     \
        xh[i] = (short)hb; xl[i] = (short)f2bh(ex[i] - bh2f(hb));            \
        hb = f2bh(ew[i]);                                                    \
        wh[i] = (short)hb; wl[i] = (short)f2bh(ew[i] - bh2f(hb));            \
      }                                                                      \
      *(s4v*)&xh_s[t * 72 + cg * 4] = xh;                                    \
      *(s4v*)&xl_s[t * 72 + cg * 4] = xl;                                    \
      *(s4v*)&wh_s[t * 72 + cg * 4] = wh;                                    \
      *(s4v*)&wl_s[t * 72 + cg * 4] = wl;                                    \
    }                                                                        \
  }

#define G1_MFMA(buf)                                                         \
  {                                                                          \
    unsigned short* xh_s = (buf);                                            \
    unsigned short* xl_s = (buf) + 64 * 72;                                  \
    unsigned short* wh_s = (buf) + 2 * 64 * 72;                              \
    unsigned short* wl_s = (buf) + 3 * 64 * 72;                              \
    _Pragma("unroll") for (int ks = 0; ks < 2; ++ks) {                       \
      const int col = ks * 32 + lq * 8;                                      \
      s8v ah[2], al[2], bh[2], bl[2];                                        \
      _Pragma("unroll") for (int i = 0; i < 2; ++i) {                        \
        ah[i] = *(const s8v*)&xh_s[(th * 32 + i * 16 + lm) * 72 + col];      \
        al[i] = *(const s8v*)&xl_s[(th * 32 + i * 16 + lm) * 72 + col];      \
        bh[i] = *(const s8v*)&wh_s[(kh * 32 + i * 16 + lm) * 72 + col];      \
        bl[i] = *(const s8v*)&wl_s[(kh * 32 + i * 16 + lm) * 72 + col];      \
      }                                                                      \
      _Pragma("unroll") for (int i = 0; i < 2; ++i)                          \
          _Pragma("unroll") for (int j = 0; j < 2; ++j) {                    \
        acc[i][j] = MFMA16(ah[i], bh[j], acc[i][j]);                         \
        acc[i][j] = MFMA16(ah[i], bl[j], acc[i][j]);                         \
        acc[i][j] = MFMA16(al[i], bh[j], acc[i][j]);                         \
      }                                                                      \
    }                                                                        \
  }

  G1_LOAD(0, 0);
  G1_STAGE(sm0, 0);
  G1_LOAD(1, 64);
  __syncthreads();
  // chunk j lives in reg-set (j&1) and LDS buffer (j&1); one barrier/chunk.
  for (int c0 = 0; c0 < C; c0 += 128) {
    // body A: compute chunk c0 from sm0; stage chunk c0+64 into sm1
    if (c0 + 128 < C) G1_LOAD(0, c0 + 128);
    G1_STAGE(sm1, 1);
    G1_MFMA(sm0);
    __syncthreads();
    // body B: compute chunk c0+64 from sm1; stage chunk c0+128 into sm0
    if (c0 + 192 < C) G1_LOAD(1, c0 + 192);
    if (c0 + 128 < C) G1_STAGE(sm0, 0);
    G1_MFMA(sm1);
    __syncthreads();
  }
#undef G1_LOAD
#undef G1_STAGE
#undef G1_MFMA

  // logits + bias -> Ls[64 t][68] fp32 (in sm0); a^T hi/lo staging in sm1.
  float* Ls = (float*)sm0;                       // 17408 B
  unsigned short* L2h = sm1;                     // [64 k][72 t] 9216 B
  unsigned short* L2l = sm1 + 64 * 72;           // 9216 B
  const float bias[2] = {b[kh * 32 + lm], b[kh * 32 + 16 + lm]};
#pragma unroll
  for (int i = 0; i < 2; ++i)
#pragma unroll
    for (int j = 0; j < 2; ++j)
#pragma unroll
      for (int r = 0; r < 4; ++r)
        Ls[(th * 32 + i * 16 + lq * 4 + r) * 68 + kh * 32 + j * 16 + lm] =
            acc[i][j][r] + bias[j];
  __syncthreads();

  // softmax: 4 threads per t-row, 16 k each, register + shfl
  {
    const int row = tid >> 2, q = tid & 3;
    float av[16];
#pragma unroll
    for (int u = 0; u < 4; ++u)
      *(float4*)&av[u * 4] = *(const float4*)&Ls[row * 68 + q * 16 + u * 4];
    float m = av[0];
#pragma unroll
    for (int i = 1; i < 16; ++i) m = fmaxf(m, av[i]);
    m = fmaxf(m, __shfl_xor(m, 1, 64));
    m = fmaxf(m, __shfl_xor(m, 2, 64));
    float sum = 0.f;
#pragma unroll
    for (int i = 0; i < 16; ++i) {
      av[i] = __expf(av[i] - m);
      sum += av[i];
    }
    sum += __shfl_xor(sum, 1, 64);
    sum += __shfl_xor(sum, 2, 64);
    const float inv = 1.f / sum;
    float ps[16];
#pragma unroll
    for (int i = 0; i < 16; ++i) {
      av[i] *= inv;
      ps[i] = av[i];
      const unsigned short hb = f2bh(av[i]);
      L2h[(q * 16 + i) * 72 + row] = hb;                       // a^T hi
      L2l[(q * 16 + i) * 72 + row] = f2bh(av[i] - bh2f(hb));   // a^T lo
    }
#pragma unroll
    for (int s = 4; s < 64; s <<= 1)
#pragma unroll
      for (int i = 0; i < 16; ++i) ps[i] += __shfl_xor(ps[i], s, 64);
    if (lane < 4) {
#pragma unroll
      for (int i = 0; i < 16; ++i) asum_l[w * 64 + q * 16 + i] = ps[i];
    }
  }
  __syncthreads();

  if (tid < 64) {
    asum_part[(n * 16 + tl) * 64 + tid] = asum_l[tid] + asum_l[64 + tid] +
                                          asum_l[128 + tid] + asum_l[192 + tid];
  }
  {
    const int k = tid >> 2, tg = tid & 3;
    const long gb = ((long)n * K + k) * T + tl * 64 + tg * 16;
    *(s8v*)&aTh[gb] = *(const s8v*)&L2h[k * 72 + tg * 16];
    *(s8v*)&aTh[gb + 8] = *(const s8v*)&L2h[k * 72 + tg * 16 + 8];
    *(s8v*)&aTl[gb] = *(const s8v*)&L2l[k * 72 + tg * 16];
    *(s8v*)&aTl[gb + 8] = *(const s8v*)&L2l[k * 72 + tg * 16 + 8];
  }
}

// ---------------------------------------------------------------------------
// k_gemm2: vlad[n,k,c] = sum_t a[t,k]*x[t,c] - asum*cent, full T per block.
// R5: double-buffered LDS, one barrier per 64-t tile (was 2); a-staging is a
// pure b128 copy from pre-split aTh/aTl (zero conversions in the loop).
// 256 thr, grid N*16 XCD-grouped. Wave = 32k x 16c, acc[2]. Fused epilogue.
// ---------------------------------------------------------------------------
__global__ __launch_bounds__(256, 4) void k_gemm2(
    const float* __restrict__ x, const unsigned short* __restrict__ aTh,
    const unsigned short* __restrict__ aTl,
    const float* __restrict__ asum_part, const float* __restrict__ cent,
    float* __restrict__ vlad, float* __restrict__ ssq_part) {
  __shared__ __align__(16) unsigned short smA[(2 * 64 + 2 * 32) * 72];  // 27648 B
  __shared__ __align__(16) unsigned short smB[(2 * 64 + 2 * 32) * 72];  // 27648 B
  __shared__ float asum_l[64];
  __shared__ float ssq_l[128];

  const int tid = threadIdx.x;
  const int w = tid >> 6, lane = tid & 63, lm = lane & 15, lq = lane >> 4;
  const int kh = w >> 1;  // 32k half
  const int ch = w & 1;   // 16c half
  // XCD-grouping bijection: all 16 c-chunk blocks of an n on one XCD
  const int p = blockIdx.x;
  const int g = p >> 3;
  const int n = ((g & 3) << 3) | (p & 7);
  const int cq = g >> 2;
  const int c0 = cq * 32;

  if (tid < 64) {
    float s = 0.f;
#pragma unroll
    for (int tl = 0; tl < 16; ++tl) s += asum_part[(n * 16 + tl) * 64 + tid];
    asum_l[tid] = s;
  }

  f4v acc[2] = {};
  const int ak = tid >> 2, atg = tid & 3;  // a-copy mapping: 16+16 ushorts
  s8v pah0[2], pal0[2], pah1[2], pal1[2];
  float4 px0[2], px1[2];

#define G2_LOAD(s, t0)                                                       \
  {                                                                          \
    const long ab = ((long)n * K + ak) * T + (t0) + atg * 16;                \
    pah##s[0] = *(const s8v*)&aTh[ab];                                       \
    pah##s[1] = *(const s8v*)&aTh[ab + 8];                                   \
    pal##s[0] = *(const s8v*)&aTl[ab];                                       \
    pal##s[1] = *(const s8v*)&aTl[ab + 8];                                   \
    const int cg = tid & 7, tq = tid >> 3;                                   \
    _Pragma("unroll") for (int i = 0; i < 2; ++i)                            \
        px##s[i] = *(const float4*)&x[((long)n * T + (t0) + tq * 2 + i) * C +\
                                      c0 + cg * 4];                          \
  }

#define G2_STAGE(buf, s)                                                     \
  {                                                                          \
    unsigned short* ah_s = (buf);                                            \
    unsigned short* al_s = (buf) + 64 * 72;                                  \
    unsigned short* xh_s = (buf) + 2 * 64 * 72;                              \
    unsigned short* xl_s = (buf) + 2 * 64 * 72 + 32 * 72;                    \
    *(s8v*)&ah_s[ak * 72 + atg * 16] = pah##s[0];                            \
    *(s8v*)&ah_s[ak * 72 + atg * 16 + 8] = pah##s[1];                        \
    *(s8v*)&al_s[ak * 72 + atg * 16] = pal##s[0];                            \
    *(s8v*)&al_s[ak * 72 + atg * 16 + 8] = pal##s[1];                        \
    const int cg = tid & 7, tq = tid >> 3;                                   \
    _Pragma("unroll") for (int cc = 0; cc < 4; ++cc) {                       \
      s2v h, l;                                                              \
      _Pragma("unroll") for (int i = 0; i < 2; ++i) {                        \
        const float e = ((const float*)&px##s[i])[cc];                       \
        const unsigned short hb = f2bh(e);                                   \
        h[i] = (short)hb;                                                    \
        l[i] = (short)f2bh(e - bh2f(hb));                                    \
      }                                                                      \
      *(s2v*)&xh_s[(cg * 4 + cc) * 72 + tq * 2] = h;                         \
      *(s2v*)&xl_s[(cg * 4 + cc) * 72 + tq * 2] = l;                         \
    }                                                                        \
  }

#define G2_MFMA(buf)                                                         \
  {                                                                          \
    unsigned short* ah_s = (buf);                                            \
    unsigned short* al_s = (buf) + 64 * 72;                                  \
    unsigned short* xh_s = (buf) + 2 * 64 * 72;                              \
    unsigned short* xl_s = (buf) + 2 * 64 * 72 + 32 * 72;                    \
    _Pragma("unroll") for (int ks = 0; ks < 2; ++ks) {                       \
      const int col = ks * 32 + lq * 8;                                      \
      s8v ah[2], al[2];                                                      \
      _Pragma("unroll") for (int i = 0; i < 2; ++i) {                        \
        ah[i] = *(const s8v*)&ah_s[(kh * 32 + i * 16 + lm) * 72 + col];      \
        al[i] = *(const s8v*)&al_s[(kh * 32 + i * 16 + lm) * 72 + col];      \
      }                                                                      \
      const s8v bh = *(const s8v*)&xh_s[(ch * 16 + lm) * 72 + col];          \
      const s8v bl = *(const s8v*)&xl_s[(ch * 16 + lm) * 72 + col];          \
      _Pragma("unroll") for (int i = 0; i < 2; ++i) {                        \
        acc[i] = MFMA16(ah[i], bh, acc[i]);                                  \
        acc[i] = MFMA16(ah[i], bl, acc[i]);                                  \
        acc[i] = MFMA16(al[i], bh, acc[i]);                                  \
      }                                                                      \
    }                                                                        \
  }

  G2_LOAD(0, 0);
  G2_STAGE(smA, 0);
  G2_LOAD(1, 64);
  __syncthreads();
  for (int t0 = 0; t0 < T; t0 += 128) {
    // body A: compute tile t0 from smA; stage tile t0+64 into smB
    if (t0 + 128 < T) G2_LOAD(0, t0 + 128);
    G2_STAGE(smB, 1);
    G2_MFMA(smA);
    __syncthreads();
    // body B: compute tile t0+64 from smB; stage tile t0+128 into smA
    if (t0 + 192 < T) G2_LOAD(1, t0 + 192);
    if (t0 + 128 < T) G2_STAGE(smA, 0);
    G2_MFMA(smB);
    __syncthreads();
  }
#undef G2_LOAD
#undef G2_STAGE
#undef G2_MFMA

  // fused epilogue: subtract asum*cent, write vlad, ssq partials
  float ssqp[2][4];
#pragma unroll
  for (int i = 0; i < 2; ++i) {
#pragma unroll
    for (int r = 0; r < 4; ++r) {
      const int k = kh * 32 + i * 16 + lq * 4 + r;
      const float as = asum_l[k];
      const int c = c0 + ch * 16 + lm;
      const float v = acc[i][r] - as * cent[(long)k * C + c];
      vlad[((long)n * K + k) * C + c] = v;
      ssqp[i][r] = v * v;
    }
  }
#pragma unroll
  for (int i = 0; i < 2; ++i)
#pragma unroll
    for (int r = 0; r < 4; ++r) {
      float s = ssqp[i][r];
      s += __shfl_xor(s, 1, 64);
      s += __shfl_xor(s, 2, 64);
      s += __shfl_xor(s, 4, 64);
      s += __shfl_xor(s, 8, 64);
      ssqp[i][r] = s;
    }
  if (lm == 0) {
#pragma unroll
    for (int i = 0; i < 2; ++i)
#pragma unroll
      for (int r = 0; r < 4; ++r)
        ssq_l[(kh * 32 + i * 16 + lq * 4 + r) * 2 + ch] = ssqp[i][r];
  }
  __syncthreads();
  if (tid < 64)
    ssq_part[(n * 16 + cq) * 64 + tid] = ssq_l[tid * 2] + ssq_l[tid * 2 + 1];
}

// ---------------------------------------------------------------------------
// k_norm: out = vlad / (||vlad_k|| * ||intra-normed||). Grid N*16 x 256.
// ---------------------------------------------------------------------------
__global__ __launch_bounds__(256) void k_norm(
    const float* __restrict__ vlad, const float* __restrict__ ssq_part,
    float* __restrict__ out) {
  __shared__ float denom[64];
  __shared__ float contrib[64];
  __shared__ float ginv;

  const int tid = threadIdx.x;
  const int n = blockIdx.x >> 4;
  const int chunk = blockIdx.x & 15;

  if (tid < 64) {
    float ss = 0.f;
#pragma unroll
    for (int q = 0; q < 16; ++q) ss += ssq_part[(n * 16 + q) * 64 + tid];
    const float d = fmaxf(sqrtf(ss), EPS);
    denom[tid] = d;
    contrib[tid] = ss / (d * d);
  }
  __syncthreads();
  if (tid == 0) {
    float s = 0.f;
#pragma unroll
    for (int k = 0; k < K; ++k) s += contrib[k];
    ginv = 1.0f / fmaxf(sqrtf(s), EPS);
  }
  __syncthreads();

#pragma unroll
  for (int q = 0; q < 2; ++q) {
    const int f4 = tid + q * 256;
    const long off = chunk * 2048 + (long)f4 * 4;
    const int k = (int)(off >> 9);
    float4 v = *(const float4*)&vlad[(long)n * K * C + off];
    const float sc = ginv / denom[k];
    v.x *= sc; v.y *= sc; v.z *= sc; v.w *= sc;
    *(float4*)&out[(long)n * K * C + off] = v;
  }
}

}  // namespace

extern "C" void kernel_launch(void* const* d_in, const int* in_sizes, int n_in,
                              void* d_out, int out_size, void* d_ws,
                              size_t ws_size, hipStream_t stream) {
  const float* x = reinterpret_cast<const float*>(d_in[0]);     // [N,T,C]
  const float* W = reinterpret_cast<const float*>(d_in[1]);     // [K,C]
  const float* b = reinterpret_cast<const float*>(d_in[2]);     // [K]
  const float* cent = reinterpret_cast<const float*>(d_in[3]);  // [K,C]
  float* out = reinterpret_cast<float*>(d_out);                 // [N, K*C]

  char* pp = reinterpret_cast<char*>(d_ws);
  unsigned short* aTh = reinterpret_cast<unsigned short*>(pp);
  pp += (size_t)N * K * T * sizeof(unsigned short);  // 4 MiB
  unsigned short* aTl = reinterpret_cast<unsigned short*>(pp);
  pp += (size_t)N * K * T * sizeof(unsigned short);  // 4 MiB
  float* vlad = reinterpret_cast<float*>(pp);
  pp += (size_t)N * K * C * sizeof(float);           // 4 MiB
  float* asum_part = reinterpret_cast<float*>(pp);
  pp += (size_t)512 * 64 * sizeof(float);            // 128 KiB
  float* ssq_part = reinterpret_cast<float*>(pp);    // 128 KiB

  k_gemm1<<<(N * T) / 64, 256, 0, stream>>>(x, W, b, aTh, aTl, asum_part);
  k_gemm2<<<N * 16, 256, 0, stream>>>(x, aTh, aTl, asum_part, cent, vlad,
                                      ssq_part);
  k_norm<<<N * 16, 256, 0, stream>>>(vlad, ssq_part, out);
}